// Round 7
// baseline (212.073 us; speedup 1.0000x reference)
//
#include <hip/hip_runtime.h>
#include <math.h>

#define Bn 2048
#define Dn 512
#define Cn 16384

typedef float v4f __attribute__((ext_vector_type(4)));

// ================= prep: 4 rows/wave, loads hoisted for MLP =================

__device__ __forceinline__ void prep_load(
    int row, int lane, const float* __restrict__ w, const float* __restrict__ x,
    float4& a, float4& b)
{
  const float* src = (row < Cn) ? (w + (size_t)row * Dn) : (x + (size_t)(row - Cn) * Dn);
  const float4* s4 = (const float4*)src;
  a = s4[lane * 2];
  b = s4[lane * 2 + 1];
}

__device__ __forceinline__ void prep_row_vals(
    int row, int lane, float4 a, float4 b,
    char* __restrict__ wq8, char* __restrict__ xq8,
    float* __restrict__ fscale, float* __restrict__ ysqA, float* __restrict__ yrA,
    float* __restrict__ xsA, float* __restrict__ xrA)
{
  bool isW = row < Cn;
  float ss = a.x * a.x + a.y * a.y + a.z * a.z + a.w * a.w
           + b.x * b.x + b.y * b.y + b.z * b.z + b.w * b.w;
  #pragma unroll
  for (int d = 1; d < 64; d <<= 1) ss += __shfl_xor(ss, d);

  int w0 = __builtin_amdgcn_cvt_pk_fp8_f32(a.x * 16.f, a.y * 16.f, 0, false);
  w0     = __builtin_amdgcn_cvt_pk_fp8_f32(a.z * 16.f, a.w * 16.f, w0, true);
  int w1 = __builtin_amdgcn_cvt_pk_fp8_f32(b.x * 16.f, b.y * 16.f, 0, false);
  w1     = __builtin_amdgcn_cvt_pk_fp8_f32(b.z * 16.f, b.w * 16.f, w1, true);
  char* dst = isW ? (wq8 + (size_t)row * Dn) : (xq8 + (size_t)(row - Cn) * Dn);
  ((int2*)dst)[lane] = make_int2(w0, w1);

  if (lane == 0) {
    if (isW) {
      float n = fmaxf(sqrtf(ss), 1e-7f);
      // fast tanh: t = (e^{2n}-1)/(e^{2n}+1); clamp arg (tanh(10)==1 in fp32)
      float e2 = __expf(2.f * fminf(n, 10.f));
      float t = (e2 - 1.f) * __builtin_amdgcn_rcpf(e2 + 1.f);
      float tc = fminf(t, 0.95f);   // radius clip folded into scale
      fscale[row] = tc / n;
      float ys = tc * tc;
      ysqA[row] = ys;
      yrA[row] = 1.f / (1.f - fminf(ys, 1.f - 1e-5f));
    } else {
      int r = row - Cn;
      xsA[r] = ss;
      xrA[r] = 1.f / (1.f - fminf(ss, 1.f - 1e-5f));
    }
  }
}

// ================= R7 GEMM: barrier-free, LDS-free, L2 register streaming ===
// Rationale: operands are 9 MB fp8, fully L2-resident (FETCH_SIZE ~= one input
// read). LDS staging only amortizes HBM -- here it was pure overhead, and its
// barrier drain (all waves wait vmcnt(0)+lgkmcnt(0) per K-step) was the
// documented ~60% stall of the 128^2 structure. Each lane now loads its MFMA
// fragments straight from global/L2 with 32-bit offsets + compile-time
// immediates ((kt*64 + s*32) <= 480 < 4096 fits the 13-bit signed offset).
// Fragment bytes are IDENTICAL to the proven LDS path (global k-bytes
// = kt*64 + s*32 + quad*8 of row base+i*16+l16), so MFMA order/operands are
// bit-identical -> same numerics. No __syncthreads anywhere: waves free-run,
// 12 waves/CU hide L2 latency (the thing the lockstep structure prevented).
// Registers: 64 frag (double-buffer) + 64 acc + 8 offsets ~= 150 -> 3 w/SIMD.
__device__ __forceinline__ void gemm_job(
    int job, int tid,
    const char* __restrict__ xq8, const char* __restrict__ wq8,
    const float* __restrict__ fscale, const float* __restrict__ ysqA,
    const float* __restrict__ yrA, const float* __restrict__ xsA,
    const float* __restrict__ xrA, float* __restrict__ partials)
{
  const int xcd = job & 7;
  const int loc = job >> 3;
  const int mt  = loc & 15;
  const int nt  = (xcd << 4) | (loc >> 4);
  const int mBase = mt * 128;
  const int nBase = nt * 128;
  const int lane = tid & 63;
  const int wv = tid >> 6;
  const int quad = lane >> 4;
  const int l16 = lane & 15;
  const int waveM = wv >> 1;
  const int waveN = wv & 1;

  v4f acc[4][4];
  #pragma unroll
  for (int i = 0; i < 4; ++i)
    #pragma unroll
    for (int j = 0; j < 4; ++j)
      acc[i][j] = (v4f){0.f, 0.f, 0.f, 0.f};

  // per-lane 32-bit fragment base offsets (row * 512 + quad*8)
  unsigned offA[4], offB[4];
  #pragma unroll
  for (int i = 0; i < 4; ++i) {
    offA[i] = (unsigned)((mBase + waveM * 64 + i * 16 + l16) * Dn + quad * 8);
    offB[i] = (unsigned)((nBase + waveN * 64 + i * 16 + l16) * Dn + quad * 8);
  }

  // double-buffered fragments: [buf][i][s], 8B each
  long a[2][4][2], b[2][4][2];
  #pragma unroll
  for (int i = 0; i < 4; ++i)
    #pragma unroll
    for (int s = 0; s < 2; ++s) {
      a[0][i][s] = *(const long*)(xq8 + offA[i] + s * 32);
      b[0][i][s] = *(const long*)(wq8 + offB[i] + s * 32);
    }

  #pragma unroll
  for (int kt = 0; kt < 8; ++kt) {
    const int cur = kt & 1;
    const int nxt = cur ^ 1;
    if (kt < 7) {  // prefetch kt+1 fragments while kt's MFMAs run
      #pragma unroll
      for (int i = 0; i < 4; ++i)
        #pragma unroll
        for (int s = 0; s < 2; ++s) {
          a[nxt][i][s] = *(const long*)(xq8 + offA[i] + (kt + 1) * 64 + s * 32);
          b[nxt][i][s] = *(const long*)(wq8 + offB[i] + (kt + 1) * 64 + s * 32);
        }
    }
    #pragma unroll
    for (int s = 0; s < 2; ++s)
      #pragma unroll
      for (int i = 0; i < 4; ++i)
        #pragma unroll
        for (int j = 0; j < 4; ++j)
          acc[i][j] = __builtin_amdgcn_mfma_f32_16x16x32_fp8_fp8(
              a[cur][i][s], b[cur][j][s], acc[i][j], 0, 0, 0);
  }

  // epilogue: e^{+64}-scaled partial sums; 1/256 folds the 16x prescale
  float ysqj[4], yrj[4], gj[4];
  #pragma unroll
  for (int j = 0; j < 4; ++j) {
    int col = nBase + waveN * 64 + j * 16 + l16;
    gj[j] = -2.f * fscale[col] * (1.f / 256.f);
    ysqj[j] = ysqA[col];
    yrj[j] = yrA[col];
  }
  #pragma unroll
  for (int i = 0; i < 4; ++i) {
    #pragma unroll
    for (int r = 0; r < 4; ++r) {
      int row = mBase + waveM * 64 + i * 16 + quad * 4 + r;
      float xs = xsA[row];
      float xr2 = 2.f * xrA[row];
      float partial = 0.f;
      if (xs >= 0.99999f) {
        // clipped row (common: ||x||^2 ~ 1.28): z large -> sims~=1/(2z)
        #pragma unroll
        for (int j = 0; j < 4; ++j) {
          float d = fmaxf(fmaf(gj[j], acc[i][j][r], xs + ysqj[j]), 0.f);
          float z = fmaf(d, xr2 * yrj[j], 1.f);
          float u = 64.f * __builtin_amdgcn_rcpf(z);
          partial += fmaf(u, fmaf(0.5f, u, 1.f), 1.f);
        }
      } else {
        #pragma unroll
        for (int j = 0; j < 4; ++j) {
          float d = fmaxf(fmaf(gj[j], acc[i][j][r], xs + ysqj[j]), 0.f);
          float z = fmaf(d, xr2 * yrj[j], 1.f);
          float sq = sqrtf(fmaf(z, z, -1.f));
          float u = 128.f * __builtin_amdgcn_rcpf(z + sq);
          partial += __expf(u);
        }
      }
      partial += __shfl_xor(partial, 1);
      partial += __shfl_xor(partial, 2);
      partial += __shfl_xor(partial, 4);
      partial += __shfl_xor(partial, 8);
      if (l16 == 0) partials[(size_t)row * 256 + nt * 2 + waveN] = partial;
    }
  }
}

// ================= kernels =================

// prep: 4 consecutive rows per wave; all 8 row-loads issued before any reduce
// (MLP x4), then 4 independent reduce/convert chains (ILP x4). Also zeroes
// `out` (stream order guarantees it precedes final's atomics).
__global__ __launch_bounds__(256) void prep_kernel(
    const float* __restrict__ w, const float* __restrict__ x,
    char* __restrict__ wq8, char* __restrict__ xq8,
    float* __restrict__ fscale, float* __restrict__ ysqA, float* __restrict__ yrA,
    float* __restrict__ xsA, float* __restrict__ xrA, float* __restrict__ out)
{
  if (blockIdx.x == 0 && threadIdx.x == 0) *out = 0.f;
  const int lane = threadIdx.x & 63;
  const int base = (blockIdx.x * 4 + (threadIdx.x >> 6)) * 4;  // wave's first row
  float4 a[4], b[4];
  #pragma unroll
  for (int i = 0; i < 4; ++i) prep_load(base + i, lane, w, x, a[i], b[i]);
  #pragma unroll
  for (int i = 0; i < 4; ++i)
    prep_row_vals(base + i, lane, a[i], b[i], wq8, xq8, fscale, ysqA, yrA, xsA, xrA);
}

__global__ __launch_bounds__(256, 3) void gemm_kernel(
    const char* __restrict__ xq8, const char* __restrict__ wq8,
    const float* __restrict__ fscale, const float* __restrict__ ysqA,
    const float* __restrict__ yrA, const float* __restrict__ xsA,
    const float* __restrict__ xrA, float* __restrict__ partials)
{
  gemm_job(blockIdx.x, threadIdx.x, xq8, wq8, fscale, ysqA, yrA, xsA, xrA, partials);
}

// final: 2 rows per wave, all global loads hoisted ahead of the shuffle reduces.
__global__ __launch_bounds__(256) void final_kernel(
    const float* __restrict__ x, const float* __restrict__ w,
    const int* __restrict__ labels, const float* __restrict__ fscale,
    const float* __restrict__ ysqA, const float* __restrict__ yrA,
    const float* __restrict__ xsA, const float* __restrict__ xrA,
    const float* __restrict__ partials, float* __restrict__ out)
{
  const int lane = threadIdx.x & 63;
  const int wvid = threadIdx.x >> 6;
  const int r0 = (blockIdx.x * 4 + wvid) * 2;
  const int r1 = r0 + 1;

  // hoisted loads
  const int lab0 = labels[r0], lab1 = labels[r1];
  const float* pr0 = partials + (size_t)r0 * 256;
  const float* pr1 = partials + (size_t)r1 * 256;
  float sum0 = pr0[lane] + pr0[lane + 64] + pr0[lane + 128] + pr0[lane + 192];
  float sum1 = pr1[lane] + pr1[lane + 64] + pr1[lane + 128] + pr1[lane + 192];

  const float4* xv0 = (const float4*)(x + (size_t)r0 * Dn);
  const float4* xv1 = (const float4*)(x + (size_t)r1 * Dn);
  const float4* wv0 = (const float4*)(w + (size_t)lab0 * Dn);
  const float4* wv1 = (const float4*)(w + (size_t)lab1 * Dn);
  float4 a00 = xv0[lane * 2], a01 = xv0[lane * 2 + 1];
  float4 b00 = wv0[lane * 2], b01 = wv0[lane * 2 + 1];
  float4 a10 = xv1[lane * 2], a11 = xv1[lane * 2 + 1];
  float4 b10 = wv1[lane * 2], b11 = wv1[lane * 2 + 1];
  float dot0 = a00.x * b00.x + a00.y * b00.y + a00.z * b00.z + a00.w * b00.w
             + a01.x * b01.x + a01.y * b01.y + a01.z * b01.z + a01.w * b01.w;
  float dot1 = a10.x * b10.x + a10.y * b10.y + a10.z * b10.z + a10.w * b10.w
             + a11.x * b11.x + a11.y * b11.y + a11.z * b11.z + a11.w * b11.w;

  #pragma unroll
  for (int d = 1; d < 64; d <<= 1) {
    sum0 += __shfl_xor(sum0, d);
    dot0 += __shfl_xor(dot0, d);
    sum1 += __shfl_xor(sum1, d);
    dot1 += __shfl_xor(dot1, d);
  }

  float term = 0.f;
  if (lane == 0) {
    #pragma unroll
    for (int h = 0; h < 2; ++h) {
      const int row = h ? r1 : r0;
      const int lab = h ? lab1 : lab0;
      const float sum = h ? sum1 : sum0;
      const float dot = h ? dot1 : dot0;
      float xy = fscale[lab] * dot;
      float diff = fmaxf(xsA[row] + ysqA[lab] - 2.f * xy, 0.f);
      float z = fmaf(2.f * diff, xrA[row] * yrA[lab], 1.f);
      float sq = sqrtf(fmaf(z, z, -1.f));
      float sims = 1.f / (z + sq);
      float u_lab = 128.f * sims;
      float cosv = fmaf(2.f, sims, -1.f);
      float sine = sqrtf(fmaxf(fmaf(-cosv, cosv, 1.f), 1e-7f));
      float phi = (cosv > -0.8775825619f)
                      ? (cosv * 0.8775825619f - sine * 0.4794255386f)
                      : (cosv - 0.2397127693f);
      float e_lab = __expf(u_lab);
      float e_phi = __expf(fminf(64.f * phi + 64.f, 80.f));
      term += logf(sum - e_lab + e_phi) - 64.f * phi - 64.f;
    }
  }

  __shared__ float red[4];
  if (lane == 0) red[wvid] = term;
  __syncthreads();
  if (threadIdx.x == 0)
    atomicAdd(out, (red[0] + red[1] + red[2] + red[3]) * (1.f / (float)Bn));
}

extern "C" void kernel_launch(void* const* d_in, const int* in_sizes, int n_in,
                              void* d_out, int out_size, void* d_ws, size_t ws_size,
                              hipStream_t stream) {
  (void)in_sizes; (void)n_in; (void)out_size; (void)ws_size;
  const float* emb = (const float*)d_in[0];
  const int* labels = (const int*)d_in[1];
  const float* weight = (const float*)d_in[2];
  float* out = (float*)d_out;

  char* p = (char*)d_ws;
  char* wq8 = p; p += (size_t)Cn * Dn;       // 8 MB fp8
  char* xq8 = p; p += (size_t)Bn * Dn;       // 1 MB fp8
  float* fscale = (float*)p; p += (size_t)Cn * 4;
  float* ysqA  = (float*)p; p += (size_t)Cn * 4;
  float* yrA   = (float*)p; p += (size_t)Cn * 4;
  float* xsA   = (float*)p; p += (size_t)Bn * 4;
  float* xrA   = (float*)p; p += (size_t)Bn * 4;
  float* partials = (float*)p; p += (size_t)Bn * 256 * 4;  // 2 MB, written-once

  // prep zeroes `out` (stream-ordered before final) — no memset dispatch
  prep_kernel<<<(Cn + Bn) / 16, 256, 0, stream>>>(weight, emb, wq8, xq8, fscale, ysqA, yrA, xsA, xrA, out);
  gemm_kernel<<<(Bn / 128) * (Cn / 128), 256, 0, stream>>>(
      xq8, wq8, fscale, ysqA, yrA, xsA, xrA, partials);
  final_kernel<<<Bn / 8, 256, 0, stream>>>(emb, weight, labels, fscale, ysqA, yrA, xsA, xrA, partials, out);
}

// Round 8
// 135.376 us; speedup vs baseline: 1.5665x; 1.5665x over previous
//
#include <hip/hip_runtime.h>
#include <math.h>

#define Bn 2048
#define Dn 512
#define Cn 16384

typedef float v4f __attribute__((ext_vector_type(4)));
typedef long lv2 __attribute__((ext_vector_type(2)));

// ===== fp8 operand storage: MFMA-fragment panel layout =====
// panel = 16 rows x 512 k-bytes = 8192 B. k-chunk c = k>>3 (8B granules).
// byte(r, k) -> (r>>4)*8192 + (c>>3)*1024 + (c&3)*256 + (r&15)*16 + ((c>>2)&1)*8
// Lane (quad,l16) fragment for (kt,s) needs chunk kt*8+s*4+quad  ->  the two
// s-halves are ONE aligned 16B word at panel + kt*1024 + quad*256 + l16*16,
// and a wave's 64 lanes cover a contiguous 1KB block (full coalescing).

// ================= prep: 4 rows/wave, loads hoisted for MLP =================

__device__ __forceinline__ void prep_load(
    int row, int lane, const float* __restrict__ w, const float* __restrict__ x,
    float4& a, float4& b)
{
  const float* src = (row < Cn) ? (w + (size_t)row * Dn) : (x + (size_t)(row - Cn) * Dn);
  const float4* s4 = (const float4*)src;
  a = s4[lane * 2];
  b = s4[lane * 2 + 1];
}

__device__ __forceinline__ void prep_row_vals(
    int row, int lane, float4 a, float4 b,
    char* __restrict__ wq8, char* __restrict__ xq8,
    float* __restrict__ fscale, float* __restrict__ ysqA, float* __restrict__ yrA,
    float* __restrict__ xsA, float* __restrict__ xrA)
{
  bool isW = row < Cn;
  float ss = a.x * a.x + a.y * a.y + a.z * a.z + a.w * a.w
           + b.x * b.x + b.y * b.y + b.z * b.z + b.w * b.w;
  #pragma unroll
  for (int d = 1; d < 64; d <<= 1) ss += __shfl_xor(ss, d);

  int w0 = __builtin_amdgcn_cvt_pk_fp8_f32(a.x * 16.f, a.y * 16.f, 0, false);
  w0     = __builtin_amdgcn_cvt_pk_fp8_f32(a.z * 16.f, a.w * 16.f, w0, true);
  int w1 = __builtin_amdgcn_cvt_pk_fp8_f32(b.x * 16.f, b.y * 16.f, 0, false);
  w1     = __builtin_amdgcn_cvt_pk_fp8_f32(b.z * 16.f, b.w * 16.f, w1, true);

  // this lane's int2 is k-chunk c = lane of its row; write to fragment layout
  int r = isW ? row : row - Cn;
  char* qb = isW ? wq8 : xq8;
  char* dst = qb + (size_t)(r >> 4) * 8192
            + ((lane >> 3) << 10) + ((lane & 3) << 8)
            + ((r & 15) << 4) + (((lane >> 2) & 1) << 3);
  *(int2*)dst = make_int2(w0, w1);

  if (lane == 0) {
    if (isW) {
      float n = fmaxf(sqrtf(ss), 1e-7f);
      // fast tanh: t = (e^{2n}-1)/(e^{2n}+1); clamp arg (tanh(10)==1 in fp32)
      float e2 = __expf(2.f * fminf(n, 10.f));
      float t = (e2 - 1.f) * __builtin_amdgcn_rcpf(e2 + 1.f);
      float tc = fminf(t, 0.95f);   // radius clip folded into scale
      fscale[row] = tc / n;
      float ys = tc * tc;
      ysqA[row] = ys;
      yrA[row] = 1.f / (1.f - fminf(ys, 1.f - 1e-5f));
    } else {
      xsA[r] = ss;
      xrA[r] = 1.f / (1.f - fminf(ss, 1.f - 1e-5f));
    }
  }
}

// ================= R8 GEMM: barrier-free, LDS-free, COALESCED L2 streaming ===
// R7's 3x regression was access shape, not concept: per-lane row-strided 8B
// loads amplified L2 line traffic 8x (64 lanes x 64B lines for 512B useful =
// measured 132us). With operands pre-stored in fragment order (see layout
// above), each lane issues ONE aligned dwordx4 per (kt,i) and the wave reads
// a contiguous 1KB block: L2 traffic back to ~512MB =~ 15us, overlapped with
// the ~17us MFMA floor by 12 free-running waves/CU. Fragment bytes and MFMA
// accumulation order are bit-identical to the proven LDS kernel.
__device__ __forceinline__ void gemm_job(
    int job, int tid,
    const char* __restrict__ xq8, const char* __restrict__ wq8,
    const float* __restrict__ fscale, const float* __restrict__ ysqA,
    const float* __restrict__ yrA, const float* __restrict__ xsA,
    const float* __restrict__ xrA, float* __restrict__ partials)
{
  const int xcd = job & 7;
  const int loc = job >> 3;
  const int mt  = loc & 15;
  const int nt  = (xcd << 4) | (loc >> 4);
  const int mBase = mt * 128;
  const int nBase = nt * 128;
  const int lane = tid & 63;
  const int wv = tid >> 6;
  const int quad = lane >> 4;
  const int l16 = lane & 15;
  const int waveM = wv >> 1;
  const int waveN = wv & 1;

  v4f acc[4][4];
  #pragma unroll
  for (int i = 0; i < 4; ++i)
    #pragma unroll
    for (int j = 0; j < 4; ++j)
      acc[i][j] = (v4f){0.f, 0.f, 0.f, 0.f};

  // per-(i) panel base pointers; per-kt step is +1024B (compile-time)
  const char* pA[4];
  const char* pB[4];
  #pragma unroll
  for (int i = 0; i < 4; ++i) {
    pA[i] = xq8 + (size_t)(((mBase + waveM * 64) >> 4) + i) * 8192
          + (quad << 8) + (l16 << 4);
    pB[i] = wq8 + (size_t)(((nBase + waveN * 64) >> 4) + i) * 8192
          + (quad << 8) + (l16 << 4);
  }

  // double-buffered fragments: lv2[i] = {s=0 chunk, s=1 chunk}
  lv2 a[2][4], b[2][4];
  #pragma unroll
  for (int i = 0; i < 4; ++i) {
    a[0][i] = *(const lv2*)(pA[i]);
    b[0][i] = *(const lv2*)(pB[i]);
  }

  #pragma unroll
  for (int kt = 0; kt < 8; ++kt) {
    const int cur = kt & 1;
    const int nxt = cur ^ 1;
    if (kt < 7) {  // prefetch kt+1 while kt's MFMAs run
      #pragma unroll
      for (int i = 0; i < 4; ++i) {
        a[nxt][i] = *(const lv2*)(pA[i] + (kt + 1) * 1024);
        b[nxt][i] = *(const lv2*)(pB[i] + (kt + 1) * 1024);
      }
    }
    #pragma unroll
    for (int s = 0; s < 2; ++s)
      #pragma unroll
      for (int i = 0; i < 4; ++i)
        #pragma unroll
        for (int j = 0; j < 4; ++j)
          acc[i][j] = __builtin_amdgcn_mfma_f32_16x16x32_fp8_fp8(
              a[cur][i][s], b[cur][j][s], acc[i][j], 0, 0, 0);
  }

  // epilogue: e^{+64}-scaled partial sums; 1/256 folds the 16x prescale
  float ysqj[4], yrj[4], gj[4];
  #pragma unroll
  for (int j = 0; j < 4; ++j) {
    int col = nBase + waveN * 64 + j * 16 + l16;
    gj[j] = -2.f * fscale[col] * (1.f / 256.f);
    ysqj[j] = ysqA[col];
    yrj[j] = yrA[col];
  }
  #pragma unroll
  for (int i = 0; i < 4; ++i) {
    #pragma unroll
    for (int r = 0; r < 4; ++r) {
      int row = mBase + waveM * 64 + i * 16 + quad * 4 + r;
      float xs = xsA[row];
      float xr2 = 2.f * xrA[row];
      float partial = 0.f;
      if (xs >= 0.99999f) {
        // clipped row (common: ||x||^2 ~ 1.28): z large -> sims~=1/(2z)
        #pragma unroll
        for (int j = 0; j < 4; ++j) {
          float d = fmaxf(fmaf(gj[j], acc[i][j][r], xs + ysqj[j]), 0.f);
          float z = fmaf(d, xr2 * yrj[j], 1.f);
          float u = 64.f * __builtin_amdgcn_rcpf(z);
          partial += fmaf(u, fmaf(0.5f, u, 1.f), 1.f);
        }
      } else {
        #pragma unroll
        for (int j = 0; j < 4; ++j) {
          float d = fmaxf(fmaf(gj[j], acc[i][j][r], xs + ysqj[j]), 0.f);
          float z = fmaf(d, xr2 * yrj[j], 1.f);
          float sq = sqrtf(fmaf(z, z, -1.f));
          float u = 128.f * __builtin_amdgcn_rcpf(z + sq);
          partial += __expf(u);
        }
      }
      partial += __shfl_xor(partial, 1);
      partial += __shfl_xor(partial, 2);
      partial += __shfl_xor(partial, 4);
      partial += __shfl_xor(partial, 8);
      if (l16 == 0) partials[(size_t)row * 256 + nt * 2 + waveN] = partial;
    }
  }
}

// ================= kernels =================

__global__ __launch_bounds__(256) void prep_kernel(
    const float* __restrict__ w, const float* __restrict__ x,
    char* __restrict__ wq8, char* __restrict__ xq8,
    float* __restrict__ fscale, float* __restrict__ ysqA, float* __restrict__ yrA,
    float* __restrict__ xsA, float* __restrict__ xrA, float* __restrict__ out)
{
  if (blockIdx.x == 0 && threadIdx.x == 0) *out = 0.f;
  const int lane = threadIdx.x & 63;
  const int base = (blockIdx.x * 4 + (threadIdx.x >> 6)) * 4;  // wave's first row
  float4 a[4], b[4];
  #pragma unroll
  for (int i = 0; i < 4; ++i) prep_load(base + i, lane, w, x, a[i], b[i]);
  #pragma unroll
  for (int i = 0; i < 4; ++i)
    prep_row_vals(base + i, lane, a[i], b[i], wq8, xq8, fscale, ysqA, yrA, xsA, xrA);
}

__global__ __launch_bounds__(256, 3) void gemm_kernel(
    const char* __restrict__ xq8, const char* __restrict__ wq8,
    const float* __restrict__ fscale, const float* __restrict__ ysqA,
    const float* __restrict__ yrA, const float* __restrict__ xsA,
    const float* __restrict__ xrA, float* __restrict__ partials)
{
  gemm_job(blockIdx.x, threadIdx.x, xq8, wq8, fscale, ysqA, yrA, xsA, xrA, partials);
}

// final: 2 rows per wave, all global loads hoisted ahead of the shuffle reduces.
__global__ __launch_bounds__(256) void final_kernel(
    const float* __restrict__ x, const float* __restrict__ w,
    const int* __restrict__ labels, const float* __restrict__ fscale,
    const float* __restrict__ ysqA, const float* __restrict__ yrA,
    const float* __restrict__ xsA, const float* __restrict__ xrA,
    const float* __restrict__ partials, float* __restrict__ out)
{
  const int lane = threadIdx.x & 63;
  const int wvid = threadIdx.x >> 6;
  const int r0 = (blockIdx.x * 4 + wvid) * 2;
  const int r1 = r0 + 1;

  // hoisted loads
  const int lab0 = labels[r0], lab1 = labels[r1];
  const float* pr0 = partials + (size_t)r0 * 256;
  const float* pr1 = partials + (size_t)r1 * 256;
  float sum0 = pr0[lane] + pr0[lane + 64] + pr0[lane + 128] + pr0[lane + 192];
  float sum1 = pr1[lane] + pr1[lane + 64] + pr1[lane + 128] + pr1[lane + 192];

  const float4* xv0 = (const float4*)(x + (size_t)r0 * Dn);
  const float4* xv1 = (const float4*)(x + (size_t)r1 * Dn);
  const float4* wv0 = (const float4*)(w + (size_t)lab0 * Dn);
  const float4* wv1 = (const float4*)(w + (size_t)lab1 * Dn);
  float4 a00 = xv0[lane * 2], a01 = xv0[lane * 2 + 1];
  float4 b00 = wv0[lane * 2], b01 = wv0[lane * 2 + 1];
  float4 a10 = xv1[lane * 2], a11 = xv1[lane * 2 + 1];
  float4 b10 = wv1[lane * 2], b11 = wv1[lane * 2 + 1];
  float dot0 = a00.x * b00.x + a00.y * b00.y + a00.z * b00.z + a00.w * b00.w
             + a01.x * b01.x + a01.y * b01.y + a01.z * b01.z + a01.w * b01.w;
  float dot1 = a10.x * b10.x + a10.y * b10.y + a10.z * b10.z + a10.w * b10.w
             + a11.x * b11.x + a11.y * b11.y + a11.z * b11.z + a11.w * b11.w;

  #pragma unroll
  for (int d = 1; d < 64; d <<= 1) {
    sum0 += __shfl_xor(sum0, d);
    dot0 += __shfl_xor(dot0, d);
    sum1 += __shfl_xor(sum1, d);
    dot1 += __shfl_xor(dot1, d);
  }

  float term = 0.f;
  if (lane == 0) {
    #pragma unroll
    for (int h = 0; h < 2; ++h) {
      const int row = h ? r1 : r0;
      const int lab = h ? lab1 : lab0;
      const float sum = h ? sum1 : sum0;
      const float dot = h ? dot1 : dot0;
      float xy = fscale[lab] * dot;
      float diff = fmaxf(xsA[row] + ysqA[lab] - 2.f * xy, 0.f);
      float z = fmaf(2.f * diff, xrA[row] * yrA[lab], 1.f);
      float sq = sqrtf(fmaf(z, z, -1.f));
      float sims = 1.f / (z + sq);
      float u_lab = 128.f * sims;
      float cosv = fmaf(2.f, sims, -1.f);
      float sine = sqrtf(fmaxf(fmaf(-cosv, cosv, 1.f), 1e-7f));
      float phi = (cosv > -0.8775825619f)
                      ? (cosv * 0.8775825619f - sine * 0.4794255386f)
                      : (cosv - 0.2397127693f);
      float e_lab = __expf(u_lab);
      float e_phi = __expf(fminf(64.f * phi + 64.f, 80.f));
      term += logf(sum - e_lab + e_phi) - 64.f * phi - 64.f;
    }
  }

  __shared__ float red[4];
  if (lane == 0) red[wvid] = term;
  __syncthreads();
  if (threadIdx.x == 0)
    atomicAdd(out, (red[0] + red[1] + red[2] + red[3]) * (1.f / (float)Bn));
}

extern "C" void kernel_launch(void* const* d_in, const int* in_sizes, int n_in,
                              void* d_out, int out_size, void* d_ws, size_t ws_size,
                              hipStream_t stream) {
  (void)in_sizes; (void)n_in; (void)out_size; (void)ws_size;
  const float* emb = (const float*)d_in[0];
  const int* labels = (const int*)d_in[1];
  const float* weight = (const float*)d_in[2];
  float* out = (float*)d_out;

  char* p = (char*)d_ws;
  char* wq8 = p; p += (size_t)Cn * Dn;       // 8 MB fp8, fragment-panel layout
  char* xq8 = p; p += (size_t)Bn * Dn;       // 1 MB fp8, fragment-panel layout
  float* fscale = (float*)p; p += (size_t)Cn * 4;
  float* ysqA  = (float*)p; p += (size_t)Cn * 4;
  float* yrA   = (float*)p; p += (size_t)Cn * 4;
  float* xsA   = (float*)p; p += (size_t)Bn * 4;
  float* xrA   = (float*)p; p += (size_t)Bn * 4;
  float* partials = (float*)p; p += (size_t)Bn * 256 * 4;  // 2 MB, written-once

  // prep zeroes `out` (stream-ordered before final) — no memset dispatch
  prep_kernel<<<(Cn + Bn) / 16, 256, 0, stream>>>(weight, emb, wq8, xq8, fscale, ysqA, yrA, xsA, xrA, out);
  gemm_kernel<<<(Bn / 128) * (Cn / 128), 256, 0, stream>>>(
      xq8, wq8, fscale, ysqA, yrA, xsA, xrA, partials);
  final_kernel<<<Bn / 8, 256, 0, stream>>>(emb, weight, labels, fscale, ysqA, yrA, xsA, xrA, partials, out);
}